// Round 1
// baseline (269260.791 us; speedup 1.0000x reference)
//
#include <hip/hip_runtime.h>
#include <hip/hip_bf16.h>
#include <stdint.h>

// Problem constants (fixed by setup_inputs)
constexpr int NB_IMG = 8;        // batch
constexpr int NCH    = 19;       // channels/classes
constexpr int HWP    = 262144;   // 512*512
constexpr int CCAP   = 152;      // max eligible (image,class) pairs: 8*18=144, cap 152
constexpr int NVMAX  = 32;       // MAX_VIEWS
constexpr int NBGEN  = 6600;     // MT19937 624-blocks to generate
constexpr int NDRAWS = NBGEN * 624;  // 4,118,400 draws (expected use ~2.9M)

// meta[] layout (ints)
constexpr int M_TOTAL = 0;
constexpr int M_NVIEW = 1;
constexpr int MB_B  = 16 + 0*CCAP;
constexpr int MB_C  = 16 + 1*CCAP;
constexpr int MB_NH = 16 + 2*CCAP;
constexpr int MB_NE = 16 + 3*CCAP;
constexpr int MB_KH = 16 + 4*CCAP;
constexpr int MB_KE = 16 + 5*CCAP;
constexpr int MB_OH = 16 + 6*CCAP;
constexpr int MB_OE = 16 + 7*CCAP;
constexpr int MB_JH = 16 + 8*CCAP;
constexpr int MB_JE = 16 + 9*CCAP;
constexpr int MB_GC = 16 + 10*CCAP;        // per-class-value group count [19]
constexpr int MB_GL = 16 + 10*CCAP + 32;   // group lists [19][8]

// ---------------- K1: argmax predict + per-(b,c) histograms ----------------
__global__ __launch_bounds__(256) void k1_argmax_hist(
    const float* __restrict__ x, const int* __restrict__ lab,
    uint8_t* __restrict__ pred, int* __restrict__ cnt, int* __restrict__ nhc) {
  __shared__ int hc[NCH], hh[NCH];
  int tid = threadIdx.x;
  if (tid < NCH) { hc[tid] = 0; hh[tid] = 0; }
  __syncthreads();
  int g = blockIdx.x * 256 + tid;          // global pixel in [0, B*HW)
  int b = g / HWP, p = g - b * HWP;        // block stays within one image (HW%256==0)
  const float* ip = x + (size_t)b * NCH * HWP + p;
  float best = ip[0]; int am = 0;
  #pragma unroll
  for (int c = 1; c < NCH; ++c) {
    float v = ip[(size_t)c * HWP];
    if (v > best) { best = v; am = c; }    // strict > keeps FIRST max (numpy argmax)
  }
  pred[g] = (uint8_t)am;
  int l = lab[g];
  atomicAdd(&hc[l], 1);
  if (am != l) atomicAdd(&hh[l], 1);
  __syncthreads();
  if (tid < NCH) {
    if (hc[tid]) atomicAdd(&cnt[b * NCH + tid], hc[tid]);
    if (hh[tid]) atomicAdd(&nhc[b * NCH + tid], hh[tid]);
  }
}

// ---------------- K2: eligibility, n_view, offsets, kh/ke, groups ----------------
__global__ void k2_meta(const int* __restrict__ cnt, const int* __restrict__ nhc,
                        int* __restrict__ meta) {
  if (threadIdx.x != 0 || blockIdx.x != 0) return;
  int total = 0, Ltot = 0, Jtot = 0;
  for (int b = 0; b < NB_IMG; ++b)
    for (int c = 1; c < NCH; ++c) {        // c==0 is IGNORE; np.unique is ascending
      int ct = cnt[b * NCH + c];
      if (ct > NVMAX) {                    // strictly > MAX_VIEWS
        int nh = nhc[b * NCH + c], ne = ct - nh;
        meta[MB_B + total] = b;  meta[MB_C + total] = c;
        meta[MB_NH + total] = nh; meta[MB_NE + total] = ne;
        meta[MB_OH + total] = Ltot; Ltot += nh;
        meta[MB_OE + total] = Ltot; Ltot += ne;
        meta[MB_JH + total] = Jtot; Jtot += (nh > 1 ? nh - 1 : 0);
        meta[MB_JE + total] = Jtot; Jtot += (ne > 1 ? ne - 1 : 0);
        ++total;
      }
    }
  int nv = 4096 / total; if (nv > NVMAX) nv = NVMAX;
  meta[M_TOTAL] = total; meta[M_NVIEW] = nv;
  for (int c = 0; c < NCH; ++c) meta[MB_GC + c] = 0;
  for (int k = 0; k < total; ++k) {
    int c = meta[MB_C + k];
    meta[MB_GL + c * 8 + meta[MB_GC + c]] = k;
    meta[MB_GC + c] += 1;
    int nh = meta[MB_NH + k], ne = meta[MB_NE + k], kh, ke;
    if (2 * nh >= nv && 2 * ne >= nv) { kh = nv / 2; ke = nv - kh; }
    else if (2 * nh >= nv)            { ke = ne;     kh = nv - ne; }
    else if (2 * ne >= nv)            { kh = nh;     ke = nv - nh; }
    else                              { kh = (nh < nv ? nh : nv); ke = nv - kh; }
    meta[MB_KH + k] = kh; meta[MB_KE + k] = ke;
  }
}

// ---------------- K3: sorted hard/easy pixel lists (stable compaction) ----------------
__global__ __launch_bounds__(256) void k3_lists(
    const int* __restrict__ lab, const uint8_t* __restrict__ pred,
    const int* __restrict__ meta, int* __restrict__ lists) {
  int k = blockIdx.x;
  if (k >= meta[M_TOTAL]) return;
  int b = meta[MB_B + k], c = meta[MB_C + k];
  int Oh = meta[MB_OH + k], Oe = meta[MB_OE + k];
  __shared__ int wH[4], wE[4];
  __shared__ int runH, runE;
  int tid = threadIdx.x;
  if (tid == 0) { runH = 0; runE = 0; }
  __syncthreads();
  const int* L = lab + (size_t)b * HWP;
  const uint8_t* P = pred + (size_t)b * HWP;
  int lane = tid & 63, w = tid >> 6;
  unsigned long long ltm = (1ull << lane) - 1ull;
  for (int base = 0; base < HWP; base += 256) {
    int p = base + tid;
    int lv = L[p];
    int pv = P[p];
    bool h = (lv == c) && (pv != c);
    bool e = (lv == c) && (pv == c);
    unsigned long long mh = __ballot(h);
    unsigned long long me = __ballot(e);
    if (lane == 0) { wH[w] = __popcll(mh); wE[w] = __popcll(me); }
    __syncthreads();
    int preH = 0, preE = 0;
    for (int i = 0; i < w; ++i) { preH += wH[i]; preE += wE[i]; }
    if (h) lists[Oh + runH + preH + __popcll(mh & ltm)] = p;
    if (e) lists[Oe + runE + preE + __popcll(me & ltm)] = p;
    __syncthreads();
    if (tid == 0) {
      runH += wH[0] + wH[1] + wH[2] + wH[3];
      runE += wE[0] + wE[1] + wE[2] + wE[3];
    }
    __syncthreads();
  }
}

// ---------------- K4: MT19937 (numpy legacy, seed 0) stream generation ----------------
// One block; per 624-block the twist is done in 3 hazard-free stages (new[i] for
// i>=227 depends on new[i-227]; element 623 uses NEW mt[0] and NEW mt[396]).
__global__ __launch_bounds__(256) void k4_mtgen(uint32_t* __restrict__ out) {
  __shared__ uint32_t mA[624], mB[624];
  int tid = threadIdx.x;
  if (tid == 0) {                           // mt19937_seed(0): Knuth init
    uint32_t prev = 0u; mA[0] = 0u;
    for (int i = 1; i < 624; ++i) {
      prev = 1812433253u * (prev ^ (prev >> 30)) + (uint32_t)i;
      mA[i] = prev;
    }
  }
  __syncthreads();
  uint32_t* cur = mA; uint32_t* nxt = mB;
  for (int blk = 0; blk < NBGEN; ++blk) {
    if (tid < 227) {
      int i = tid;
      uint32_t y = (cur[i] & 0x80000000u) | (cur[i + 1] & 0x7fffffffu);
      nxt[i] = cur[i + 397] ^ (y >> 1) ^ ((y & 1u) ? 0x9908b0dfu : 0u);
    }
    __syncthreads();
    if (tid < 227) {
      int i = 227 + tid;
      uint32_t y = (cur[i] & 0x80000000u) | (cur[i + 1] & 0x7fffffffu);
      nxt[i] = nxt[i - 227] ^ (y >> 1) ^ ((y & 1u) ? 0x9908b0dfu : 0u);
    }
    __syncthreads();
    if (tid < 170) {
      int i = 454 + tid;
      uint32_t y;
      if (i < 623) y = (cur[i] & 0x80000000u) | (cur[i + 1] & 0x7fffffffu);
      else         y = (cur[623] & 0x80000000u) | (nxt[0] & 0x7fffffffu);
      nxt[i] = nxt[i - 227] ^ (y >> 1) ^ ((y & 1u) ? 0x9908b0dfu : 0u);
    }
    __syncthreads();
    for (int i = tid; i < 624; i += 256) {  // temper + store
      uint32_t y = nxt[i];
      y ^= y >> 11;
      y ^= (y << 7)  & 0x9d2c5680u;
      y ^= (y << 15) & 0xefc60000u;
      y ^= y >> 18;
      out[blk * 624 + i] = y;
    }
    __syncthreads();
    uint32_t* t = cur; cur = nxt; nxt = t;
  }
}

// ---------------- K5: serial consumption automaton (random_interval replay) ----------------
// All 64 lanes compute identically (uniform values -> scalarization-friendly);
// lane 0 records each accepted j. Records only transpositions; swaps recovered in K6.
__global__ __launch_bounds__(64) void k5_consume(
    const uint32_t* __restrict__ stream, const int* __restrict__ meta,
    uint32_t* __restrict__ J) {
  int total = meta[M_TOTAL];
  int t = 0;
  for (int k = 0; k < total; ++k) {
    for (int ph = 0; ph < 2; ++ph) {
      int n  = ph ? meta[MB_NE + k] : meta[MB_NH + k];
      int jb = ph ? meta[MB_JE + k] : meta[MB_JH + k];
      if (n < 2) continue;
      uint32_t i = (uint32_t)(n - 1);
      uint32_t mask = i;
      mask |= mask >> 1; mask |= mask >> 2; mask |= mask >> 4;
      mask |= mask >> 8; mask |= mask >> 16;
      uint32_t half = mask >> 1;
      int s = 0;
      for (; i >= 1u; --i) {
        uint32_t v;
        do { v = stream[t++] & mask; } while (v > i);   // rejection sampling
        if (threadIdx.x == 0) J[jb + s] = v;
        ++s;
        if ((i - 1u) <= half) { mask = half; half >>= 1; }
      }
    }
  }
}

// ---------------- K6: backward provenance walk -> selected pixel per (class,view) ----------------
__global__ __launch_bounds__(64) void k6_walk(
    const uint32_t* __restrict__ J, const int* __restrict__ meta,
    const int* __restrict__ lists, int* __restrict__ sel) {
  int k = blockIdx.x;
  if (k >= meta[M_TOTAL]) return;
  int nv = meta[M_NVIEW];
  int vi = threadIdx.x;
  if (vi >= nv) return;
  int kh = meta[MB_KH + k];
  int n, off, p;
  const uint32_t* Jb;
  if (vi < kh) { n = meta[MB_NH + k]; Jb = J + meta[MB_JH + k]; off = meta[MB_OH + k]; p = vi; }
  else         { n = meta[MB_NE + k]; Jb = J + meta[MB_JE + k]; off = meta[MB_OE + k]; p = vi - kh; }
  // transposition idx applied ascending (i = n-1 ... 1); trace final position p backward
  for (int idx = n - 2; idx >= 0; --idx) {
    int i = n - 1 - idx;
    int j = (int)Jb[idx];
    p = (p == i) ? j : ((p == j) ? i : p);
  }
  sel[k * NVMAX + vi] = lists[off + p];
}

// ---------------- K7: gather selected pixels + channel softmax -> cf [V*A, 19] ----------------
__global__ __launch_bounds__(64) void k7_gather(
    const float* __restrict__ x, const int* __restrict__ meta,
    const int* __restrict__ sel, float* __restrict__ cf) {
  int k = blockIdx.x;
  int total = meta[M_TOTAL];
  if (k >= total) return;
  int nv = meta[M_NVIEW];
  int vi = threadIdx.x;
  if (vi >= nv) return;
  int p = sel[k * NVMAX + vi];
  int b = meta[MB_B + k];
  const float* ip = x + (size_t)b * NCH * HWP + p;
  float v[NCH];
  float mx = -1e30f;
  #pragma unroll
  for (int c = 0; c < NCH; ++c) { v[c] = ip[(size_t)c * HWP]; mx = fmaxf(mx, v[c]); }
  float s = 0.f;
  #pragma unroll
  for (int c = 0; c < NCH; ++c) { v[c] = expf(v[c] - mx); s += v[c]; }
  float inv = 1.f / s;
  float* row = cf + (size_t)(vi * total + k) * NCH;   // cf row = v*A + a
  #pragma unroll
  for (int c = 0; c < NCH; ++c) row[c] = v[c] * inv;
}

// ---------------- K8: supervised contrastive loss, one block per row ----------------
__global__ __launch_bounds__(256) void k8_loss(
    const float* __restrict__ cf, const int* __restrict__ meta, float* __restrict__ out) {
  int A = meta[M_TOTAL], V = meta[M_NVIEW];
  int N = A * V;
  int row = blockIdx.x;
  if (row >= N) return;
  int tid = threadIdx.x;
  __shared__ float red[256], red2[256];
  __shared__ float srow[NCH];
  __shared__ float sM, sS, sNeg;
  if (tid < NCH) srow[tid] = cf[(size_t)row * NCH + tid];
  __syncthreads();
  float my[NCH];
  #pragma unroll
  for (int d = 0; d < NCH; ++d) my[d] = srow[d];
  // pass 1: online max + exp-sum over ALL columns (incl. self)
  float m = -1e30f, s = 0.f;
  for (int j = tid; j < N; j += 256) {
    const float* cj = cf + (size_t)j * NCH;
    float dot = 0.f;
    #pragma unroll
    for (int d = 0; d < NCH; ++d) dot += my[d] * cj[d];
    float l = dot / 0.07f;
    if (l > m) { s *= expf(m - l); m = l; }
    s += expf(l - m);
  }
  red[tid] = m; red2[tid] = s;
  __syncthreads();
  if (tid == 0) {
    float M = -1e30f;
    for (int i = 0; i < 256; ++i) M = fmaxf(M, red[i]);
    float S = 0.f;
    for (int i = 0; i < 256; ++i) S += red2[i] * expf(red[i] - M);
    sM = M; sS = S;
  }
  __syncthreads();
  float M = sM;
  // pass 2: positives = same class value (any image, any view); <=256 of them
  int a = row % A;
  int c = meta[MB_C + a];
  int g = meta[MB_GC + c];
  int np = g * V;
  float l = 0.f, e = 0.f;
  int j = -1;
  if (tid < np) {
    int kk = meta[MB_GL + c * 8 + tid / V];
    int v2 = tid - (tid / V) * V;
    j = v2 * A + kk;
    const float* cj = cf + (size_t)j * NCH;
    float dot = 0.f;
    #pragma unroll
    for (int d = 0; d < NCH; ++d) dot += my[d] * cj[d];
    l = dot / 0.07f - M;
    e = expf(l);
  }
  red[tid] = (tid < np) ? e : 0.f;            // sum over same-label incl. self
  __syncthreads();
  if (tid == 0) {
    float Se = 0.f;
    for (int i = 0; i < 256; ++i) Se += red[i];
    sNeg = sS - Se;                            // sum over different-label
  }
  __syncthreads();
  float neg = sNeg;
  red[tid] = (tid < np && j != row) ? (l - logf(e + neg)) : 0.f;
  __syncthreads();
  if (tid == 0) {
    float SL = 0.f;
    for (int i = 0; i < 256; ++i) SL += red[i];
    float lossRow = -(SL / (float)(np - 1));
    atomicAdd(out, lossRow / (float)N);
  }
}

// ---------------- launch ----------------
extern "C" void kernel_launch(void* const* d_in, const int* in_sizes, int n_in,
                              void* d_out, int out_size, void* d_ws, size_t ws_size,
                              hipStream_t stream) {
  const float* x  = (const float*)d_in[0];   // [8,19,512,512] f32
  const int*   tg = (const int*)d_in[1];     // [8,512,512] i32
  char* ws = (char*)d_ws;
  // workspace layout (bytes), total ~36 MB
  uint8_t*  pred  = (uint8_t*)(ws + 0);                 //  2,097,152
  int*      cnt   = (int*)(ws + 2097152);               //  608
  int*      nhc   = (int*)(ws + 2098176);               //  608
  int*      meta  = (int*)(ws + 2099200);               //  8,192
  int*      lists = (int*)(ws + 2107392);               //  8,388,608
  uint32_t* J     = (uint32_t*)(ws + 10496000);         //  8,388,608
  uint32_t* stm   = (uint32_t*)(ws + 18884608);         // 16,473,600
  int*      sel   = (int*)(ws + 35661824);              //  19,456
  float*    cf    = (float*)(ws + 35682304);            //  350,208
  float*    out   = (float*)d_out;

  hipMemsetAsync(ws + 2097152, 0, 2048, stream);   // zero cnt+nhc
  hipMemsetAsync(d_out, 0, sizeof(float), stream); // zero loss accumulator

  k1_argmax_hist<<<(NB_IMG * HWP) / 256, 256, 0, stream>>>(x, tg, pred, cnt, nhc);
  k2_meta<<<1, 64, 0, stream>>>(cnt, nhc, meta);
  k3_lists<<<CCAP, 256, 0, stream>>>(tg, pred, meta, lists);
  k4_mtgen<<<1, 256, 0, stream>>>(stm);
  k5_consume<<<1, 64, 0, stream>>>(stm, meta, J);
  k6_walk<<<CCAP, 64, 0, stream>>>(J, meta, lists, sel);
  k7_gather<<<CCAP, 64, 0, stream>>>(x, meta, sel, cf);
  k8_loss<<<CCAP * NVMAX, 256, 0, stream>>>(cf, meta, out);
}

// Round 4
// 29164.102 us; speedup vs baseline: 9.2326x; 9.2326x over previous
//
#include <hip/hip_runtime.h>
#include <hip/hip_bf16.h>
#include <stdint.h>

// Problem constants (fixed by setup_inputs)
constexpr int NB_IMG = 8;        // batch
constexpr int NCH    = 19;       // channels/classes
constexpr int HWP    = 262144;   // 512*512
constexpr int CCAP   = 152;      // max eligible (image,class) pairs: 8*18=144, cap 152
constexpr int NVMAX  = 32;       // MAX_VIEWS
constexpr int NBGEN  = 6600;     // MT19937 624-blocks to generate
constexpr int NDRAWS = NBGEN * 624;  // 4,118,400 draws (expected use ~2.9M)
constexpr int CH     = 8192;     // draws per LDS chunk (32KB; 2 buffers = 64KB)

// meta[] layout (ints)
constexpr int M_TOTAL = 0;
constexpr int M_NVIEW = 1;
constexpr int MB_B  = 16 + 0*CCAP;
constexpr int MB_C  = 16 + 1*CCAP;
constexpr int MB_NH = 16 + 2*CCAP;
constexpr int MB_NE = 16 + 3*CCAP;
constexpr int MB_KH = 16 + 4*CCAP;
constexpr int MB_KE = 16 + 5*CCAP;
constexpr int MB_OH = 16 + 6*CCAP;
constexpr int MB_OE = 16 + 7*CCAP;
constexpr int MB_JH = 16 + 8*CCAP;
constexpr int MB_JE = 16 + 9*CCAP;
constexpr int MB_GC = 16 + 10*CCAP;        // per-class-value group count [19]
constexpr int MB_GL = 16 + 10*CCAP + 32;   // group lists [19][8]

// ---------------- K1: argmax predict + per-(b,c) histograms ----------------
__global__ __launch_bounds__(256) void k1_argmax_hist(
    const float* __restrict__ x, const int* __restrict__ lab,
    uint8_t* __restrict__ pred, int* __restrict__ cnt, int* __restrict__ nhc) {
  __shared__ int hc[NCH], hh[NCH];
  int tid = threadIdx.x;
  if (tid < NCH) { hc[tid] = 0; hh[tid] = 0; }
  __syncthreads();
  int g = blockIdx.x * 256 + tid;          // global pixel in [0, B*HW)
  int b = g / HWP, p = g - b * HWP;        // block stays within one image (HW%256==0)
  const float* ip = x + (size_t)b * NCH * HWP + p;
  float best = ip[0]; int am = 0;
  #pragma unroll
  for (int c = 1; c < NCH; ++c) {
    float v = ip[(size_t)c * HWP];
    if (v > best) { best = v; am = c; }    // strict > keeps FIRST max (numpy argmax)
  }
  pred[g] = (uint8_t)am;
  int l = lab[g];
  atomicAdd(&hc[l], 1);
  if (am != l) atomicAdd(&hh[l], 1);
  __syncthreads();
  if (tid < NCH) {
    if (hc[tid]) atomicAdd(&cnt[b * NCH + tid], hc[tid]);
    if (hh[tid]) atomicAdd(&nhc[b * NCH + tid], hh[tid]);
  }
}

// ---------------- K2: eligibility, n_view, offsets, kh/ke, groups ----------------
__global__ void k2_meta(const int* __restrict__ cnt, const int* __restrict__ nhc,
                        int* __restrict__ meta) {
  if (threadIdx.x != 0 || blockIdx.x != 0) return;
  int total = 0, Ltot = 0, Jtot = 0;
  for (int b = 0; b < NB_IMG; ++b)
    for (int c = 1; c < NCH; ++c) {        // c==0 is IGNORE; np.unique is ascending
      int ct = cnt[b * NCH + c];
      if (ct > NVMAX) {                    // strictly > MAX_VIEWS
        int nh = nhc[b * NCH + c], ne = ct - nh;
        meta[MB_B + total] = b;  meta[MB_C + total] = c;
        meta[MB_NH + total] = nh; meta[MB_NE + total] = ne;
        meta[MB_OH + total] = Ltot; Ltot += nh;
        meta[MB_OE + total] = Ltot; Ltot += ne;
        meta[MB_JH + total] = Jtot; Jtot += (nh > 1 ? nh - 1 : 0);
        meta[MB_JE + total] = Jtot; Jtot += (ne > 1 ? ne - 1 : 0);
        ++total;
      }
    }
  int nv = 4096 / total; if (nv > NVMAX) nv = NVMAX;
  meta[M_TOTAL] = total; meta[M_NVIEW] = nv;
  for (int c = 0; c < NCH; ++c) meta[MB_GC + c] = 0;
  for (int k = 0; k < total; ++k) {
    int c = meta[MB_C + k];
    meta[MB_GL + c * 8 + meta[MB_GC + c]] = k;
    meta[MB_GC + c] += 1;
    int nh = meta[MB_NH + k], ne = meta[MB_NE + k], kh, ke;
    if (2 * nh >= nv && 2 * ne >= nv) { kh = nv / 2; ke = nv - kh; }
    else if (2 * nh >= nv)            { ke = ne;     kh = nv - ne; }
    else if (2 * ne >= nv)            { kh = nh;     ke = nv - nh; }
    else                              { kh = (nh < nv ? nh : nv); ke = nv - kh; }
    meta[MB_KH + k] = kh; meta[MB_KE + k] = ke;
  }
}

// ---------------- K3: sorted hard/easy pixel lists (stable compaction) ----------------
__global__ __launch_bounds__(256) void k3_lists(
    const int* __restrict__ lab, const uint8_t* __restrict__ pred,
    const int* __restrict__ meta, int* __restrict__ lists) {
  int k = blockIdx.x;
  if (k >= meta[M_TOTAL]) return;
  int b = meta[MB_B + k], c = meta[MB_C + k];
  int Oh = meta[MB_OH + k], Oe = meta[MB_OE + k];
  __shared__ int wH[4], wE[4];
  __shared__ int runH, runE;
  int tid = threadIdx.x;
  if (tid == 0) { runH = 0; runE = 0; }
  __syncthreads();
  const int* L = lab + (size_t)b * HWP;
  const uint8_t* P = pred + (size_t)b * HWP;
  int lane = tid & 63, w = tid >> 6;
  unsigned long long ltm = (1ull << lane) - 1ull;
  for (int base = 0; base < HWP; base += 256) {
    int p = base + tid;
    int lv = L[p];
    int pv = P[p];
    bool h = (lv == c) && (pv != c);
    bool e = (lv == c) && (pv == c);
    unsigned long long mh = __ballot(h);
    unsigned long long me = __ballot(e);
    if (lane == 0) { wH[w] = __popcll(mh); wE[w] = __popcll(me); }
    __syncthreads();
    int preH = 0, preE = 0;
    for (int i = 0; i < w; ++i) { preH += wH[i]; preE += wE[i]; }
    if (h) lists[Oh + runH + preH + __popcll(mh & ltm)] = p;
    if (e) lists[Oe + runE + preE + __popcll(me & ltm)] = p;
    __syncthreads();
    if (tid == 0) {
      runH += wH[0] + wH[1] + wH[2] + wH[3];
      runE += wE[0] + wE[1] + wE[2] + wE[3];
    }
    __syncthreads();
  }
}

// ---------------- K4: MT19937 (numpy legacy, seed 0) stream generation ----------------
__global__ __launch_bounds__(256) void k4_mtgen(uint32_t* __restrict__ out) {
  __shared__ uint32_t mA[624], mB[624];
  int tid = threadIdx.x;
  if (tid == 0) {                           // mt19937_seed(0): Knuth init
    uint32_t prev = 0u; mA[0] = 0u;
    for (int i = 1; i < 624; ++i) {
      prev = 1812433253u * (prev ^ (prev >> 30)) + (uint32_t)i;
      mA[i] = prev;
    }
  }
  __syncthreads();
  uint32_t* cur = mA; uint32_t* nxt = mB;
  for (int blk = 0; blk < NBGEN; ++blk) {
    if (tid < 227) {
      int i = tid;
      uint32_t y = (cur[i] & 0x80000000u) | (cur[i + 1] & 0x7fffffffu);
      nxt[i] = cur[i + 397] ^ (y >> 1) ^ ((y & 1u) ? 0x9908b0dfu : 0u);
    }
    __syncthreads();
    if (tid < 227) {
      int i = 227 + tid;
      uint32_t y = (cur[i] & 0x80000000u) | (cur[i + 1] & 0x7fffffffu);
      nxt[i] = nxt[i - 227] ^ (y >> 1) ^ ((y & 1u) ? 0x9908b0dfu : 0u);
    }
    __syncthreads();
    if (tid < 170) {
      int i = 454 + tid;
      uint32_t y;
      if (i < 623) y = (cur[i] & 0x80000000u) | (cur[i + 1] & 0x7fffffffu);
      else         y = (cur[623] & 0x80000000u) | (nxt[0] & 0x7fffffffu);
      nxt[i] = nxt[i - 227] ^ (y >> 1) ^ ((y & 1u) ? 0x9908b0dfu : 0u);
    }
    __syncthreads();
    for (int i = tid; i < 624; i += 256) {  // temper + store
      uint32_t y = nxt[i];
      y ^= y >> 11;
      y ^= (y << 7)  & 0x9d2c5680u;
      y ^= (y << 15) & 0xefc60000u;
      y ^= y >> 18;
      out[blk * 624 + i] = y;
    }
    __syncthreads();
    uint32_t* t = cur; cur = nxt; nxt = t;
  }
}

// ---------------- K5: wave-parallel rejection-automaton replay ----------------
// Stream position advances by exactly 1 per draw (accept OR reject), so the
// stream is consumed linearly: stage 32KB chunks in double-buffered LDS via
// async global_load_lds, prefetched one chunk ahead.
// Window decode: 64 (or 16) consecutive draws resolved in parallel with a
// ballot fixed-point: acc_l = (w_l <= i0 - prefix_l(acc)). From the superset
// (w_l <= i0), lane k is exact after <=k iterations (typically 2-3 total).
// Window preconditions (i >= half + W) guarantee no mask shrink and no
// segment end inside the window. Serial fallback (cached b128 quad) covers
// octave boundaries and segment tails.
__global__ __launch_bounds__(64) void k5_consume(
    const uint32_t* __restrict__ stream, const int* __restrict__ meta,
    uint32_t* __restrict__ J) {
  __shared__ __align__(16) uint32_t sbuf[2][CH];   // 64KB
  const int lane = threadIdx.x;
  const unsigned long long ltm = (1ull << lane) - 1ull;

  auto issue_chunk = [&](int ci, int nb) {
    if ((long long)(ci + 1) * CH > (long long)NDRAWS) return;
    const uint32_t* gp0 = stream + (size_t)ci * CH;
    for (int q = 0; q < CH / 256; ++q) {    // 32 issues of 64 lanes x 16B = 1KB
      const uint32_t* gp = gp0 + q * 256 + lane * 4;
      auto* lp = (__attribute__((address_space(3))) uint32_t*)&sbuf[nb][q * 256 + lane * 4];
      __builtin_amdgcn_global_load_lds(
          (const __attribute__((address_space(1))) uint32_t*)gp, lp, 16, 0, 0);
    }
  };

  issue_chunk(0, 0);
  issue_chunk(1, 1);
  asm volatile("s_waitcnt vmcnt(0)" ::: "memory");

  int tchunk = 0, c = 0, cur = 0;
  int qbase = -1; uint4 qv = make_uint4(0, 0, 0, 0);

  const int total = meta[M_TOTAL];
  for (int seg = 0; seg < 2 * total; ++seg) {
    int k = seg >> 1, ph = seg & 1;
    int n  = ph ? meta[MB_NE + k] : meta[MB_NH + k];
    int jb = ph ? meta[MB_JE + k] : meta[MB_JH + k];
    if (n < 2) continue;
    int i = n - 1;
    uint32_t mask = (uint32_t)i;
    mask |= mask >> 1; mask |= mask >> 2; mask |= mask >> 4;
    mask |= mask >> 8; mask |= mask >> 16;
    uint32_t half = mask >> 1;
    int s = 0;
    while (i >= 1) {
      if (c >= CH) {                          // chunk swap + prefetch next
        c -= CH; ++tchunk; cur ^= 1;
        asm volatile("s_waitcnt vmcnt(0)" ::: "memory");
        issue_chunk(tchunk + 1, cur ^ 1);
        qbase = -1;
      }
      int W = 0;
      if      (i >= (int)half + 64 && c + 64 <= CH) W = 64;
      else if (i >= (int)half + 16 && c + 16 <= CH) W = 16;
      if (W) {
        uint32_t v = sbuf[cur][c + (lane & (W - 1))];
        uint32_t w = v & mask;
        bool part = lane < W;
        unsigned long long A = __ballot(part && w <= (uint32_t)i);
        for (;;) {
          int pre = __popcll(A & ltm);
          unsigned long long A2 = __ballot(part && w <= (uint32_t)(i - pre));
          if (A2 == A) break;
          A = A2;
        }
        int pre = __popcll(A & ltm);
        int na = __popcll(A);
        if ((A >> lane) & 1ull) J[jb + s + pre] = w;
        s += na; i -= na; c += W;
        if (i <= (int)half) { mask = half; half >>= 1; }   // at most one shrink
      } else {
        int qb = c >> 2;
        if (qb != qbase) { qv = *(const uint4*)&sbuf[cur][qb << 2]; qbase = qb; }
        uint32_t v = (c & 2) ? ((c & 1) ? qv.w : qv.z)
                             : ((c & 1) ? qv.y : qv.x);
        ++c;
        uint32_t w = v & mask;
        if (w <= (uint32_t)i) {
          if (lane == 0) J[jb + s] = w;
          ++s; --i;
          if (i == 0) break;
          if (i <= (int)half) { mask = half; half >>= 1; }
        }
      }
    }
  }
}

// ---------------- K6: backward provenance walk -> selected pixel per (class,view) ----------------
__global__ __launch_bounds__(64) void k6_walk(
    const uint32_t* __restrict__ J, const int* __restrict__ meta,
    const int* __restrict__ lists, int* __restrict__ sel) {
  int k = blockIdx.x;
  if (k >= meta[M_TOTAL]) return;
  int nv = meta[M_NVIEW];
  int vi = threadIdx.x;
  if (vi >= nv) return;
  int kh = meta[MB_KH + k];
  int n, off, p;
  const uint32_t* Jb;
  if (vi < kh) { n = meta[MB_NH + k]; Jb = J + meta[MB_JH + k]; off = meta[MB_OH + k]; p = vi; }
  else         { n = meta[MB_NE + k]; Jb = J + meta[MB_JE + k]; off = meta[MB_OE + k]; p = vi - kh; }
  // transposition idx applied ascending (i = n-1 ... 1); trace final position p backward
  for (int idx = n - 2; idx >= 0; --idx) {
    int i = n - 1 - idx;
    int j = (int)Jb[idx];
    p = (p == i) ? j : ((p == j) ? i : p);
  }
  sel[k * NVMAX + vi] = lists[off + p];
}

// ---------------- K7: gather selected pixels + channel softmax -> cf [V*A, 19] ----------------
__global__ __launch_bounds__(64) void k7_gather(
    const float* __restrict__ x, const int* __restrict__ meta,
    const int* __restrict__ sel, float* __restrict__ cf) {
  int k = blockIdx.x;
  int total = meta[M_TOTAL];
  if (k >= total) return;
  int nv = meta[M_NVIEW];
  int vi = threadIdx.x;
  if (vi >= nv) return;
  int p = sel[k * NVMAX + vi];
  int b = meta[MB_B + k];
  const float* ip = x + (size_t)b * NCH * HWP + p;
  float v[NCH];
  float mx = -1e30f;
  #pragma unroll
  for (int c = 0; c < NCH; ++c) { v[c] = ip[(size_t)c * HWP]; mx = fmaxf(mx, v[c]); }
  float s = 0.f;
  #pragma unroll
  for (int c = 0; c < NCH; ++c) { v[c] = expf(v[c] - mx); s += v[c]; }
  float inv = 1.f / s;
  float* row = cf + (size_t)(vi * total + k) * NCH;   // cf row = v*A + a
  #pragma unroll
  for (int c = 0; c < NCH; ++c) row[c] = v[c] * inv;
}

// ---------------- K8: supervised contrastive loss, one block per row ----------------
__global__ __launch_bounds__(256) void k8_loss(
    const float* __restrict__ cf, const int* __restrict__ meta, float* __restrict__ out) {
  int A = meta[M_TOTAL], V = meta[M_NVIEW];
  int N = A * V;
  int row = blockIdx.x;
  if (row >= N) return;
  int tid = threadIdx.x;
  __shared__ float red[256], red2[256];
  __shared__ float srow[NCH];
  __shared__ float sM, sS, sNeg;
  if (tid < NCH) srow[tid] = cf[(size_t)row * NCH + tid];
  __syncthreads();
  float my[NCH];
  #pragma unroll
  for (int d = 0; d < NCH; ++d) my[d] = srow[d];
  // pass 1: online max + exp-sum over ALL columns (incl. self)
  float m = -1e30f, s = 0.f;
  for (int j = tid; j < N; j += 256) {
    const float* cj = cf + (size_t)j * NCH;
    float dot = 0.f;
    #pragma unroll
    for (int d = 0; d < NCH; ++d) dot += my[d] * cj[d];
    float l = dot / 0.07f;
    if (l > m) { s *= expf(m - l); m = l; }
    s += expf(l - m);
  }
  red[tid] = m; red2[tid] = s;
  __syncthreads();
  if (tid == 0) {
    float M = -1e30f;
    for (int i = 0; i < 256; ++i) M = fmaxf(M, red[i]);
    float S = 0.f;
    for (int i = 0; i < 256; ++i) S += red2[i] * expf(red[i] - M);
    sM = M; sS = S;
  }
  __syncthreads();
  float M = sM;
  // pass 2: positives = same class value (any image, any view); <=256 of them
  int a = row % A;
  int c = meta[MB_C + a];
  int g = meta[MB_GC + c];
  int np = g * V;
  float l = 0.f, e = 0.f;
  int j = -1;
  if (tid < np) {
    int kk = meta[MB_GL + c * 8 + tid / V];
    int v2 = tid - (tid / V) * V;
    j = v2 * A + kk;
    const float* cj = cf + (size_t)j * NCH;
    float dot = 0.f;
    #pragma unroll
    for (int d = 0; d < NCH; ++d) dot += my[d] * cj[d];
    l = dot / 0.07f - M;
    e = expf(l);
  }
  red[tid] = (tid < np) ? e : 0.f;            // sum over same-label incl. self
  __syncthreads();
  if (tid == 0) {
    float Se = 0.f;
    for (int i = 0; i < 256; ++i) Se += red[i];
    sNeg = sS - Se;                            // sum over different-label
  }
  __syncthreads();
  float neg = sNeg;
  red[tid] = (tid < np && j != row) ? (l - logf(e + neg)) : 0.f;
  __syncthreads();
  if (tid == 0) {
    float SL = 0.f;
    for (int i = 0; i < 256; ++i) SL += red[i];
    float lossRow = -(SL / (float)(np - 1));
    atomicAdd(out, lossRow / (float)N);
  }
}

// ---------------- launch ----------------
extern "C" void kernel_launch(void* const* d_in, const int* in_sizes, int n_in,
                              void* d_out, int out_size, void* d_ws, size_t ws_size,
                              hipStream_t stream) {
  const float* x  = (const float*)d_in[0];   // [8,19,512,512] f32
  const int*   tg = (const int*)d_in[1];     // [8,512,512] i32
  char* ws = (char*)d_ws;
  // workspace layout (bytes), total ~36 MB
  uint8_t*  pred  = (uint8_t*)(ws + 0);                 //  2,097,152
  int*      cnt   = (int*)(ws + 2097152);               //  608
  int*      nhc   = (int*)(ws + 2098176);               //  608
  int*      meta  = (int*)(ws + 2099200);               //  8,192
  int*      lists = (int*)(ws + 2107392);               //  8,388,608
  uint32_t* J     = (uint32_t*)(ws + 10496000);         //  8,388,608
  uint32_t* stm   = (uint32_t*)(ws + 18884608);         // 16,473,600
  int*      sel   = (int*)(ws + 35661824);              //  19,456
  float*    cf    = (float*)(ws + 35682304);            //  350,208
  float*    out   = (float*)d_out;

  hipMemsetAsync(ws + 2097152, 0, 2048, stream);   // zero cnt+nhc
  hipMemsetAsync(d_out, 0, sizeof(float), stream); // zero loss accumulator

  k1_argmax_hist<<<(NB_IMG * HWP) / 256, 256, 0, stream>>>(x, tg, pred, cnt, nhc);
  k2_meta<<<1, 64, 0, stream>>>(cnt, nhc, meta);
  k3_lists<<<CCAP, 256, 0, stream>>>(tg, pred, meta, lists);
  k4_mtgen<<<1, 256, 0, stream>>>(stm);
  k5_consume<<<1, 64, 0, stream>>>(stm, meta, J);
  k6_walk<<<CCAP, 64, 0, stream>>>(J, meta, lists, sel);
  k7_gather<<<CCAP, 64, 0, stream>>>(x, meta, sel, cf);
  k8_loss<<<CCAP * NVMAX, 256, 0, stream>>>(cf, meta, out);
}

// Round 7
// 14443.532 us; speedup vs baseline: 18.6423x; 2.0192x over previous
//
#include <hip/hip_runtime.h>
#include <hip/hip_bf16.h>
#include <stdint.h>

// Problem constants (fixed by setup_inputs)
constexpr int NB_IMG = 8;        // batch
constexpr int NCH    = 19;       // channels/classes
constexpr int HWP    = 262144;   // 512*512
constexpr int CCAP   = 152;      // max eligible (image,class) pairs: 8*18=144, cap 152
constexpr int NVMAX  = 32;       // MAX_VIEWS
constexpr int NBGEN  = 6600;     // MT19937 624-blocks to generate
constexpr int NDRAWS = NBGEN * 624;  // 4,118,400 draws (expected use ~2.75M)
constexpr int CH     = 8192;     // draws per LDS chunk (32KB; 2 buffers = 64KB)

// meta[] layout (ints)
constexpr int M_TOTAL = 0;
constexpr int M_NVIEW = 1;
constexpr int MB_B  = 16 + 0*CCAP;
constexpr int MB_C  = 16 + 1*CCAP;
constexpr int MB_NH = 16 + 2*CCAP;
constexpr int MB_NE = 16 + 3*CCAP;
constexpr int MB_KH = 16 + 4*CCAP;
constexpr int MB_KE = 16 + 5*CCAP;
constexpr int MB_OH = 16 + 6*CCAP;
constexpr int MB_OE = 16 + 7*CCAP;
constexpr int MB_JH = 16 + 8*CCAP;
constexpr int MB_JE = 16 + 9*CCAP;
constexpr int MB_GC = 16 + 10*CCAP;        // per-class-value group count [19]
constexpr int MB_GL = 16 + 10*CCAP + 32;   // group lists [19][8]

// ---------------- K1: argmax predict + per-(b,c) histograms ----------------
__global__ __launch_bounds__(256) void k1_argmax_hist(
    const float* __restrict__ x, const int* __restrict__ lab,
    uint8_t* __restrict__ pred, int* __restrict__ cnt, int* __restrict__ nhc) {
  __shared__ int hc[NCH], hh[NCH];
  int tid = threadIdx.x;
  if (tid < NCH) { hc[tid] = 0; hh[tid] = 0; }
  __syncthreads();
  int g = blockIdx.x * 256 + tid;          // global pixel in [0, B*HW)
  int b = g / HWP, p = g - b * HWP;        // block stays within one image (HW%256==0)
  const float* ip = x + (size_t)b * NCH * HWP + p;
  float best = ip[0]; int am = 0;
  #pragma unroll
  for (int c = 1; c < NCH; ++c) {
    float v = ip[(size_t)c * HWP];
    if (v > best) { best = v; am = c; }    // strict > keeps FIRST max (numpy argmax)
  }
  pred[g] = (uint8_t)am;
  int l = lab[g];
  atomicAdd(&hc[l], 1);
  if (am != l) atomicAdd(&hh[l], 1);
  __syncthreads();
  if (tid < NCH) {
    if (hc[tid]) atomicAdd(&cnt[b * NCH + tid], hc[tid]);
    if (hh[tid]) atomicAdd(&nhc[b * NCH + tid], hh[tid]);
  }
}

// ---------------- K2: eligibility, n_view, offsets, kh/ke, groups ----------------
__global__ void k2_meta(const int* __restrict__ cnt, const int* __restrict__ nhc,
                        int* __restrict__ meta) {
  if (threadIdx.x != 0 || blockIdx.x != 0) return;
  int total = 0, Ltot = 0, Jtot = 0;
  for (int b = 0; b < NB_IMG; ++b)
    for (int c = 1; c < NCH; ++c) {        // c==0 is IGNORE; np.unique is ascending
      int ct = cnt[b * NCH + c];
      if (ct > NVMAX) {                    // strictly > MAX_VIEWS
        int nh = nhc[b * NCH + c], ne = ct - nh;
        meta[MB_B + total] = b;  meta[MB_C + total] = c;
        meta[MB_NH + total] = nh; meta[MB_NE + total] = ne;
        meta[MB_OH + total] = Ltot; Ltot += nh;
        meta[MB_OE + total] = Ltot; Ltot += ne;
        meta[MB_JH + total] = Jtot; Jtot += (nh > 1 ? nh - 1 : 0);
        meta[MB_JE + total] = Jtot; Jtot += (ne > 1 ? ne - 1 : 0);
        ++total;
      }
    }
  int nv = 4096 / total; if (nv > NVMAX) nv = NVMAX;
  meta[M_TOTAL] = total; meta[M_NVIEW] = nv;
  for (int c = 0; c < NCH; ++c) meta[MB_GC + c] = 0;
  for (int k = 0; k < total; ++k) {
    int c = meta[MB_C + k];
    meta[MB_GL + c * 8 + meta[MB_GC + c]] = k;
    meta[MB_GC + c] += 1;
    int nh = meta[MB_NH + k], ne = meta[MB_NE + k], kh, ke;
    if (2 * nh >= nv && 2 * ne >= nv) { kh = nv / 2; ke = nv - kh; }
    else if (2 * nh >= nv)            { ke = ne;     kh = nv - ne; }
    else if (2 * ne >= nv)            { kh = nh;     ke = nv - nh; }
    else                              { kh = (nh < nv ? nh : nv); ke = nv - kh; }
    meta[MB_KH + k] = kh; meta[MB_KE + k] = ke;
  }
}

// ---------------- K3: sorted hard/easy pixel lists (stable compaction) ----------------
__global__ __launch_bounds__(256) void k3_lists(
    const int* __restrict__ lab, const uint8_t* __restrict__ pred,
    const int* __restrict__ meta, int* __restrict__ lists) {
  int k = blockIdx.x;
  if (k >= meta[M_TOTAL]) return;
  int b = meta[MB_B + k], c = meta[MB_C + k];
  int Oh = meta[MB_OH + k], Oe = meta[MB_OE + k];
  __shared__ int wH[4], wE[4];
  __shared__ int runH, runE;
  int tid = threadIdx.x;
  if (tid == 0) { runH = 0; runE = 0; }
  __syncthreads();
  const int* L = lab + (size_t)b * HWP;
  const uint8_t* P = pred + (size_t)b * HWP;
  int lane = tid & 63, w = tid >> 6;
  unsigned long long ltm = (1ull << lane) - 1ull;
  for (int base = 0; base < HWP; base += 256) {
    int p = base + tid;
    int lv = L[p];
    int pv = P[p];
    bool h = (lv == c) && (pv != c);
    bool e = (lv == c) && (pv == c);
    unsigned long long mh = __ballot(h);
    unsigned long long me = __ballot(e);
    if (lane == 0) { wH[w] = __popcll(mh); wE[w] = __popcll(me); }
    __syncthreads();
    int preH = 0, preE = 0;
    for (int i = 0; i < w; ++i) { preH += wH[i]; preE += wE[i]; }
    if (h) lists[Oh + runH + preH + __popcll(mh & ltm)] = p;
    if (e) lists[Oe + runE + preE + __popcll(me & ltm)] = p;
    __syncthreads();
    if (tid == 0) {
      runH += wH[0] + wH[1] + wH[2] + wH[3];
      runE += wE[0] + wE[1] + wE[2] + wE[3];
    }
    __syncthreads();
  }
}

// ---------------- K4: MT19937 (numpy legacy, seed 0) stream generation ----------------
__global__ __launch_bounds__(256) void k4_mtgen(uint32_t* __restrict__ out) {
  __shared__ uint32_t mA[624], mB[624];
  int tid = threadIdx.x;
  if (tid == 0) {                           // mt19937_seed(0): Knuth init
    uint32_t prev = 0u; mA[0] = 0u;
    for (int i = 1; i < 624; ++i) {
      prev = 1812433253u * (prev ^ (prev >> 30)) + (uint32_t)i;
      mA[i] = prev;
    }
  }
  __syncthreads();
  uint32_t* cur = mA; uint32_t* nxt = mB;
  for (int blk = 0; blk < NBGEN; ++blk) {
    if (tid < 227) {
      int i = tid;
      uint32_t y = (cur[i] & 0x80000000u) | (cur[i + 1] & 0x7fffffffu);
      nxt[i] = cur[i + 397] ^ (y >> 1) ^ ((y & 1u) ? 0x9908b0dfu : 0u);
    }
    __syncthreads();
    if (tid < 227) {
      int i = 227 + tid;
      uint32_t y = (cur[i] & 0x80000000u) | (cur[i + 1] & 0x7fffffffu);
      nxt[i] = nxt[i - 227] ^ (y >> 1) ^ ((y & 1u) ? 0x9908b0dfu : 0u);
    }
    __syncthreads();
    if (tid < 170) {
      int i = 454 + tid;
      uint32_t y;
      if (i < 623) y = (cur[i] & 0x80000000u) | (cur[i + 1] & 0x7fffffffu);
      else         y = (cur[623] & 0x80000000u) | (nxt[0] & 0x7fffffffu);
      nxt[i] = nxt[i - 227] ^ (y >> 1) ^ ((y & 1u) ? 0x9908b0dfu : 0u);
    }
    __syncthreads();
    for (int i = tid; i < 624; i += 256) {  // temper + store
      uint32_t y = nxt[i];
      y ^= y >> 11;
      y ^= (y << 7)  & 0x9d2c5680u;
      y ^= (y << 15) & 0xefc60000u;
      y ^= y >> 18;
      out[blk * 624 + i] = y;
    }
    __syncthreads();
    uint32_t* t = cur; cur = nxt; nxt = t;
  }
}

// ---------------- K5: wave-parallel rejection-automaton replay ----------------
// Dual-mask windows: a window may contain ONE mask shrink. Per lane, current
// index i_l = i0 - prefix_l(accepts); the lane's mask is half if i_l <= half
// else mask. Any ballot fixed point equals the sequential outcome (induction
// on lanes: lane l's inputs depend only on lanes < l, so the fixed point is
// unique). Precondition i0 >= W + (half>>1) + 1 bounds shrinks to <=1 and
// keeps the segment from ending mid-window. 256-draw batches (4 subwindows,
// reads issued together) amortize LDS latency and loop overhead.
__global__ __launch_bounds__(64) void k5_consume(
    const uint32_t* __restrict__ stream, const int* __restrict__ meta,
    uint32_t* __restrict__ J) {
  __shared__ __align__(16) uint32_t sbuf[2][CH];   // 64KB
  const int lane = threadIdx.x;
  const unsigned long long ltm = (1ull << lane) - 1ull;

  auto issue_chunk = [&](int ci, int nb) {
    if ((long long)(ci + 1) * CH > (long long)NDRAWS) return;
    const uint32_t* gp0 = stream + (size_t)ci * CH;
    for (int q = 0; q < CH / 256; ++q) {    // 32 issues of 64 lanes x 16B = 1KB
      const uint32_t* gp = gp0 + q * 256 + lane * 4;
      auto* lp = (__attribute__((address_space(3))) uint32_t*)&sbuf[nb][q * 256 + lane * 4];
      __builtin_amdgcn_global_load_lds(
          (const __attribute__((address_space(1))) uint32_t*)gp, lp, 16, 0, 0);
    }
  };

  issue_chunk(0, 0);
  issue_chunk(1, 1);
  asm volatile("s_waitcnt vmcnt(0)" ::: "memory");

  int tchunk = 0, c = 0, cur = 0;

  const int total = meta[M_TOTAL];
  for (int seg = 0; seg < 2 * total; ++seg) {
    int k = seg >> 1, ph = seg & 1;
    int n  = ph ? meta[MB_NE + k] : meta[MB_NH + k];
    int jb = ph ? meta[MB_JE + k] : meta[MB_JH + k];
    if (n < 2) continue;
    int i = n - 1;
    uint32_t mask = (uint32_t)i;
    mask |= mask >> 1; mask |= mask >> 2; mask |= mask >> 4;
    mask |= mask >> 8; mask |= mask >> 16;
    uint32_t half = mask >> 1;
    int s = 0;

    // resolve one W-wide subwindow starting at c (caller guarantees
    // i >= W + (half>>1) + 1 and c+W <= CH); updates i, s, c, mask, half.
    auto subwin = [&](uint32_t v, int W) {
      bool part = lane < W;
      uint32_t wm = v & mask, wh = v & half;
      unsigned long long A = __ballot(part && wm <= (uint32_t)i);
      for (;;) {
        int p = __popcll(A & ltm);
        uint32_t il = (uint32_t)(i - p);
        uint32_t w = (il <= half) ? wh : wm;
        unsigned long long A2 = __ballot(part && w <= il);
        if (A2 == A) break;
        A = A2;
      }
      int p = __popcll(A & ltm);
      uint32_t il = (uint32_t)(i - p);
      uint32_t w = (il <= half) ? wh : wm;
      if ((A >> lane) & 1ull) J[jb + s + p] = w;
      int na = __popcll(A);
      s += na; i -= na; c += W;
      if (i <= (int)half) { mask = half; half >>= 1; }   // at most one shrink
    };

    while (i >= 1) {
      if (c >= CH) {                          // chunk swap + prefetch next
        c -= CH; ++tchunk; cur ^= 1;
        asm volatile("s_waitcnt vmcnt(0)" ::: "memory");
        issue_chunk(tchunk + 1, cur ^ 1);
      }
      int hh2 = (int)(half >> 1);
      if (i >= 257 + hh2 && c + 256 <= CH) {  // 256-draw batch (<=1 shrink total)
        uint32_t v0 = sbuf[cur][c + lane];
        uint32_t v1 = sbuf[cur][c + 64 + lane];
        uint32_t v2 = sbuf[cur][c + 128 + lane];
        uint32_t v3 = sbuf[cur][c + 192 + lane];
        subwin(v0, 64); subwin(v1, 64); subwin(v2, 64); subwin(v3, 64);
        continue;
      }
      int W = 0;
      if      (i >= 65 + hh2 && c + 64 <= CH) W = 64;
      else if (i >= 17 + hh2 && c + 16 <= CH) W = 16;
      else if (i >= 5  + hh2 && c + 4  <= CH) W = 4;
      if (W) {
        uint32_t v = sbuf[cur][c + (lane & (W - 1))];
        subwin(v, W);
      } else {                                // serial draw (rare: tiny i or chunk edge)
        uint32_t v = sbuf[cur][c]; ++c;
        uint32_t w = v & mask;
        if (w <= (uint32_t)i) {
          if (lane == 0) J[jb + s] = w;
          ++s; --i;
          if (i == 0) break;
          if (i <= (int)half) { mask = half; half >>= 1; }
        }
      }
    }
  }
}

// ---------------- K6: backward provenance walk -> selected pixel per (class,view) ----------------
// J segments staged into LDS (addresses are induction-based, so the walk's
// LDS reads pipeline); global fallback if a segment exceeds the LDS budget.
__global__ __launch_bounds__(64) void k6_walk(
    const uint32_t* __restrict__ J, const int* __restrict__ meta,
    const int* __restrict__ lists, int* __restrict__ sel) {
  __shared__ uint32_t jh[14848];   // 58KB hard-stream stage
  __shared__ uint32_t je[1024];    //  4KB easy-stream stage
  int k = blockIdx.x;
  if (k >= meta[M_TOTAL]) return;
  int nv = meta[M_NVIEW];
  int vi = threadIdx.x;
  int kh = meta[MB_KH + k];
  int nh = meta[MB_NH + k], ne = meta[MB_NE + k];
  const uint32_t* Jh = J + meta[MB_JH + k];
  const uint32_t* Je = J + meta[MB_JE + k];
  int lh = nh > 1 ? nh - 1 : 0, le = ne > 1 ? ne - 1 : 0;
  bool hfit = lh <= 14848, efit = le <= 1024;
  if (hfit) for (int t = threadIdx.x; t < lh; t += 64) jh[t] = Jh[t];
  if (efit) for (int t = threadIdx.x; t < le; t += 64) je[t] = Je[t];
  __syncthreads();
  if (vi >= nv) return;
  int n, off, p;
  const uint32_t* Jb;
  if (vi < kh) { n = nh; Jb = hfit ? (const uint32_t*)jh : Jh; off = meta[MB_OH + k]; p = vi; }
  else         { n = ne; Jb = efit ? (const uint32_t*)je : Je; off = meta[MB_OE + k]; p = vi - kh; }
  // transposition idx applied ascending (i = n-1 ... 1); trace final position p backward
  #pragma unroll 8
  for (int idx = n - 2; idx >= 0; --idx) {
    int i = n - 1 - idx;
    int j = (int)Jb[idx];
    p = (p == i) ? j : ((p == j) ? i : p);
  }
  sel[k * NVMAX + vi] = lists[off + p];
}

// ---------------- K7: gather selected pixels + channel softmax -> cf [V*A, 19] ----------------
__global__ __launch_bounds__(64) void k7_gather(
    const float* __restrict__ x, const int* __restrict__ meta,
    const int* __restrict__ sel, float* __restrict__ cf) {
  int k = blockIdx.x;
  int total = meta[M_TOTAL];
  if (k >= total) return;
  int nv = meta[M_NVIEW];
  int vi = threadIdx.x;
  if (vi >= nv) return;
  int p = sel[k * NVMAX + vi];
  int b = meta[MB_B + k];
  const float* ip = x + (size_t)b * NCH * HWP + p;
  float v[NCH];
  float mx = -1e30f;
  #pragma unroll
  for (int c = 0; c < NCH; ++c) { v[c] = ip[(size_t)c * HWP]; mx = fmaxf(mx, v[c]); }
  float s = 0.f;
  #pragma unroll
  for (int c = 0; c < NCH; ++c) { v[c] = expf(v[c] - mx); s += v[c]; }
  float inv = 1.f / s;
  float* row = cf + (size_t)(vi * total + k) * NCH;   // cf row = v*A + a
  #pragma unroll
  for (int c = 0; c < NCH; ++c) row[c] = v[c] * inv;
}

// ---------------- K8: supervised contrastive loss, one block per row ----------------
__global__ __launch_bounds__(256) void k8_loss(
    const float* __restrict__ cf, const int* __restrict__ meta, float* __restrict__ out) {
  int A = meta[M_TOTAL], V = meta[M_NVIEW];
  int N = A * V;
  int row = blockIdx.x;
  if (row >= N) return;
  int tid = threadIdx.x;
  __shared__ float red[256], red2[256];
  __shared__ float srow[NCH];
  __shared__ float sM, sS, sNeg;
  if (tid < NCH) srow[tid] = cf[(size_t)row * NCH + tid];
  __syncthreads();
  float my[NCH];
  #pragma unroll
  for (int d = 0; d < NCH; ++d) my[d] = srow[d];
  // pass 1: online max + exp-sum over ALL columns (incl. self)
  float m = -1e30f, s = 0.f;
  for (int j = tid; j < N; j += 256) {
    const float* cj = cf + (size_t)j * NCH;
    float dot = 0.f;
    #pragma unroll
    for (int d = 0; d < NCH; ++d) dot += my[d] * cj[d];
    float l = dot / 0.07f;
    if (l > m) { s *= expf(m - l); m = l; }
    s += expf(l - m);
  }
  red[tid] = m; red2[tid] = s;
  __syncthreads();
  if (tid == 0) {
    float M = -1e30f;
    for (int i = 0; i < 256; ++i) M = fmaxf(M, red[i]);
    float S = 0.f;
    for (int i = 0; i < 256; ++i) S += red2[i] * expf(red[i] - M);
    sM = M; sS = S;
  }
  __syncthreads();
  float M = sM;
  // pass 2: positives = same class value (any image, any view); <=256 of them
  int a = row % A;
  int c = meta[MB_C + a];
  int g = meta[MB_GC + c];
  int np = g * V;
  float l = 0.f, e = 0.f;
  int j = -1;
  if (tid < np) {
    int kk = meta[MB_GL + c * 8 + tid / V];
    int v2 = tid - (tid / V) * V;
    j = v2 * A + kk;
    const float* cj = cf + (size_t)j * NCH;
    float dot = 0.f;
    #pragma unroll
    for (int d = 0; d < NCH; ++d) dot += my[d] * cj[d];
    l = dot / 0.07f - M;
    e = expf(l);
  }
  red[tid] = (tid < np) ? e : 0.f;            // sum over same-label incl. self
  __syncthreads();
  if (tid == 0) {
    float Se = 0.f;
    for (int i = 0; i < 256; ++i) Se += red[i];
    sNeg = sS - Se;                            // sum over different-label
  }
  __syncthreads();
  float neg = sNeg;
  red[tid] = (tid < np && j != row) ? (l - logf(e + neg)) : 0.f;
  __syncthreads();
  if (tid == 0) {
    float SL = 0.f;
    for (int i = 0; i < 256; ++i) SL += red[i];
    float lossRow = -(SL / (float)(np - 1));
    atomicAdd(out, lossRow / (float)N);
  }
}

// ---------------- launch ----------------
extern "C" void kernel_launch(void* const* d_in, const int* in_sizes, int n_in,
                              void* d_out, int out_size, void* d_ws, size_t ws_size,
                              hipStream_t stream) {
  const float* x  = (const float*)d_in[0];   // [8,19,512,512] f32
  const int*   tg = (const int*)d_in[1];     // [8,512,512] i32
  char* ws = (char*)d_ws;
  // workspace layout (bytes), total ~36 MB
  uint8_t*  pred  = (uint8_t*)(ws + 0);                 //  2,097,152
  int*      cnt   = (int*)(ws + 2097152);               //  608
  int*      nhc   = (int*)(ws + 2098176);               //  608
  int*      meta  = (int*)(ws + 2099200);               //  8,192
  int*      lists = (int*)(ws + 2107392);               //  8,388,608
  uint32_t* J     = (uint32_t*)(ws + 10496000);         //  8,388,608
  uint32_t* stm   = (uint32_t*)(ws + 18884608);         // 16,473,600
  int*      sel   = (int*)(ws + 35661824);              //  19,456
  float*    cf    = (float*)(ws + 35682304);             //  350,208
  float*    out   = (float*)d_out;

  hipMemsetAsync(ws + 2097152, 0, 2048, stream);   // zero cnt+nhc
  hipMemsetAsync(d_out, 0, sizeof(float), stream); // zero loss accumulator

  k1_argmax_hist<<<(NB_IMG * HWP) / 256, 256, 0, stream>>>(x, tg, pred, cnt, nhc);
  k2_meta<<<1, 64, 0, stream>>>(cnt, nhc, meta);
  k3_lists<<<CCAP, 256, 0, stream>>>(tg, pred, meta, lists);
  k4_mtgen<<<1, 256, 0, stream>>>(stm);
  k5_consume<<<1, 64, 0, stream>>>(stm, meta, J);
  k6_walk<<<CCAP, 64, 0, stream>>>(J, meta, lists, sel);
  k7_gather<<<CCAP, 64, 0, stream>>>(x, meta, sel, cf);
  k8_loss<<<CCAP * NVMAX, 256, 0, stream>>>(cf, meta, out);
}